// Round 8
// baseline (1584.026 us; speedup 1.0000x reference)
//
#include <hip/hip_runtime.h>
#include <hip/hip_bf16.h>

#define NODES 32768
#define HD 128
#define NE 524288
#define NR 8
#define NS 262144                          // 4 pass-halves * NODES * 2 keys
#define PASSB 65536                        // keys per pass = NODES*2

typedef unsigned int u32;
typedef unsigned short u16;
typedef __attribute__((ext_vector_type(8))) short bf16x8;
typedef __attribute__((ext_vector_type(4))) float f32x4;

// ---- ws byte offsets ----
#define XH_OFF   (0u)                      // bf16 hi x, 8 MB
#define XL_OFF   (8u<<20)                  // bf16 lo x, 8 MB
#define XH2_OFF  (16u<<20)                 // layer-1 x hi
#define XL2_OFF  (24u<<20)                 // layer-1 x lo
#define ADJ_OFF  (32u<<20)                 // u32 x NE packed (src | row<<15)
#define RP_OFF   (34u<<20)                 // u32 x (NS+1)
#define CUR_OFF  (36u<<20)                 // u32 x NS
#define BSUM_OFF (37u<<20)                 // u32 x 1025
#define BP_OFF   (38u<<20)                 // packed weights bf16

#define BP_LAYER 294912                    // 9*2*16384
#define PP_ELEM  589824                    // pW packed at Bp+PP_ELEM

__device__ __forceinline__ float bflo(u32 u){ union{u32 i;float f;}c; c.i=u<<16; return c.f; }
__device__ __forceinline__ float bfhi(u32 u){ union{u32 i;float f;}c; c.i=u&0xffff0000u; return c.f; }
__device__ __forceinline__ u16 f2bf(float f){
  u32 u=__float_as_uint(f);
  u32 r=u + 0x7fffu + ((u>>16)&1u);
  return (u16)(r>>16);
}
__device__ __forceinline__ float bf2f(u16 h){ return __uint_as_float(((u32)h)<<16); }

__device__ __forceinline__ void gl_lds16(const void* g, void* l){
  __builtin_amdgcn_global_load_lds((const __attribute__((address_space(1))) u32*)g,
                                   (__attribute__((address_space(3))) u32*)l, 16, 0, 0);
}

// hardware LDS f32 atomic add (no return) — the HIP atomicAdd on a generic
// pointer compiles to a flat/CAS path (R6: 425 us); raw ds_add_f32 streams.
__device__ __forceinline__ void ds_addf(float* p, float v){
  u32 off=(u32)(size_t)(__attribute__((address_space(3))) float*)p;
  asm volatile("ds_add_f32 %0, %1" :: "v"(off), "v"(v));
}
__device__ __forceinline__ void ds_addf_off256(float* p, float v){
  u32 off=(u32)(size_t)(__attribute__((address_space(3))) float*)p;
  asm volatile("ds_add_f32 %0, %1 offset:256" :: "v"(off), "v"(v));
}

// ---------------- weight prep: 2 layers x 9 tiles (8 rel + self) + pW, hi/lo segs ----
__global__ void prep_w(const float* __restrict__ rW, const float* __restrict__ sW,
                       const float* __restrict__ pWg, u16* __restrict__ Bp)
{
  int idx=blockIdx.x*256+threadIdx.x;           // 311296 total
  if(idx<294912){
    int l=idx/147456;
    int rem=idx%147456;
    int t=rem>>14;
    int kn=rem&16383;
    int k=kn>>7, n=kn&127;
    float w;
    if(t<8) w=rW[(((size_t)l*NR+t)*HD+n)*HD+k];
    else    w=sW[((size_t)l*HD+n)*HD+k];
    u16* base=Bp+(size_t)l*BP_LAYER+(size_t)t*32768;
    int ks=k>>5, q=(k>>3)&3, j=k&7;
    size_t off=((size_t)ks*128+n)*32+q*8+j;
    u16 hb=f2bf(w);
    u16 lb=f2bf(w-bf2f(hb));
    base[off]=hb;
    base[off+16384]=lb;
  } else {
    int kn=idx-294912;
    int k=kn>>7, n=kn&127;
    float w=pWg[(size_t)n*HD+k];
    u16* base=Bp+PP_ELEM;
    int ks=k>>5, q=(k>>3)&3, j=k&7;
    size_t off=((size_t)ks*128+n)*32+q*8+j;
    u16 hb=f2bf(w);
    u16 lb=f2bf(w-bf2f(hb));
    base[off]=hb;
    base[off+16384]=lb;
  }
}

// ---------------- embed_mfma: x = (cemb[cid]+kemb[kid]) @ pW^T + pb -> xh/xl ----------
__global__ __launch_bounds__(256,2) void embed_mfma(
    const int* __restrict__ cid, const int* __restrict__ kid,
    const float* __restrict__ cemb, const float* __restrict__ kemb,
    const u16* __restrict__ PP, const float* __restrict__ pb,
    u16* __restrict__ xh, u16* __restrict__ xl)
{
  __shared__ u16 Atile[2][128*128];   // [0]=hi [1]=lo, 64 KB, XOR-16 swizzle
  const int tid=threadIdx.x;
  const int wave=tid>>6, lane=tid&63;
  const int wm=wave>>1, wn=wave&1;
  const int q=lane>>4;
  const int d0=blockIdx.x*128;

  { int r=tid>>1, half=tid&1;
    int ci=cid[d0+r], ki=kid[d0+r];
    const float* cp=cemb+(size_t)ci*HD+half*64;
    const float* kp=kemb+(size_t)ki*HD+half*64;
#pragma unroll
    for(int cc=0;cc<8;cc++){
      float4 a0=*(const float4*)(cp+cc*8);
      float4 a1=*(const float4*)(cp+cc*8+4);
      float4 b0=*(const float4*)(kp+cc*8);
      float4 b1=*(const float4*)(kp+cc*8+4);
      float v[8]={a0.x+b0.x,a0.y+b0.y,a0.z+b0.z,a0.w+b0.w,
                  a1.x+b1.x,a1.y+b1.y,a1.z+b1.z,a1.w+b1.w};
      u16 hb[8], lb[8];
#pragma unroll
      for(int j=0;j<8;j++){ hb[j]=f2bf(v[j]); lb[j]=f2bf(v[j]-bf2f(hb[j])); }
      int chunk=half*8+cc;
      int dst=r*128+(chunk^(r&15))*8;
      uint4 hv={(u32)hb[0]|((u32)hb[1]<<16),(u32)hb[2]|((u32)hb[3]<<16),
                (u32)hb[4]|((u32)hb[5]<<16),(u32)hb[6]|((u32)hb[7]<<16)};
      uint4 lv={(u32)lb[0]|((u32)lb[1]<<16),(u32)lb[2]|((u32)lb[3]<<16),
                (u32)lb[4]|((u32)lb[5]<<16),(u32)lb[6]|((u32)lb[7]<<16)};
      *(uint4*)&Atile[0][dst]=hv;
      *(uint4*)&Atile[1][dst]=lv;
    }
  }
  __syncthreads();

  f32x4 acc[4][4];
#pragma unroll
  for(int a=0;a<4;a++)
#pragma unroll
    for(int b=0;b<4;b++) acc[a][b]=(f32x4){0.f,0.f,0.f,0.f};

#pragma unroll
  for(int ks=0;ks<4;ks++){
    bf16x8 ah[4];
#pragma unroll
    for(int tm=0;tm<4;tm++){
      int m=wm*64+tm*16+(lane&15);
      ah[tm]=*(const bf16x8*)&Atile[0][m*128+(((ks*4)+q)^(m&15))*8];
    }
#pragma unroll
    for(int s=0;s<2;s++){
      const u16* Bb=PP+s*16384;
#pragma unroll
      for(int tn=0;tn<4;tn++){
        int n=wn*64+tn*16+(lane&15);
        bf16x8 bfr=*(const bf16x8*)&Bb[((size_t)ks*128+n)*32+q*8];
#pragma unroll
        for(int tm=0;tm<4;tm++)
          acc[tm][tn]=__builtin_amdgcn_mfma_f32_16x16x32_bf16(ah[tm],bfr,acc[tm][tn],0,0,0);
      }
    }
  }
#pragma unroll
  for(int ks=0;ks<4;ks++){
    bf16x8 al[4];
#pragma unroll
    for(int tm=0;tm<4;tm++){
      int m=wm*64+tm*16+(lane&15);
      al[tm]=*(const bf16x8*)&Atile[1][m*128+(((ks*4)+q)^(m&15))*8];
    }
#pragma unroll
    for(int tn=0;tn<4;tn++){
      int n=wn*64+tn*16+(lane&15);
      bf16x8 bfr=*(const bf16x8*)&PP[((size_t)ks*128+n)*32+q*8];
#pragma unroll
      for(int tm=0;tm<4;tm++)
        acc[tm][tn]=__builtin_amdgcn_mfma_f32_16x16x32_bf16(al[tm],bfr,acc[tm][tn],0,0,0);
    }
  }

  // ---- epilogue: +pb, hi/lo split into dead Atile (swz bits5-6), linear dwordx4 out ----
  __syncthreads();
  { u16* Sh=(u16*)Atile[0];
    u16* Sl=(u16*)Atile[1];
#pragma unroll
    for(int tn=0;tn<4;tn++){
      int n=wn*64+tn*16+(lane&15);
      float b=pb[n];
#pragma unroll
      for(int tm=0;tm<4;tm++){
        int rbase=wm*64+tm*16+q*4;
#pragma unroll
        for(int r=0;r<4;r++){
          float v=acc[tm][tn][r]+b;
          u16 hb=f2bf(v);
          u16 lb=f2bf(v-bf2f(hb));
          int row=rbase+r;
          u32 ab=(u32)(row*256+n*2);
          ab^=((u32)((row>>2)&3))<<5;
          Sh[ab>>1]=hb;
          Sl[ab>>1]=lb;
        }
      }
    }
  }
  __syncthreads();
  { const char* S0=(const char*)Atile[0];
    const char* S1=(const char*)Atile[1];
    char* xhb=(char*)(xh+(size_t)d0*HD);
    char* xlb=(char*)(xl+(size_t)d0*HD);
#pragma unroll
    for(int i=0;i<8;i++){
      u32 byte=(u32)(i*256+tid)*16;       // 32 KB tile, 16 lanes = one 256B row
      u32 row=byte>>8;
      u32 lb2=byte^((((row>>2)&3))<<5);
      *(uint4*)(xhb+byte)=*(const uint4*)(S0+lb2);
      *(uint4*)(xlb+byte)=*(const uint4*)(S1+lb2);
    }
  }
}

// ---------------- CSR build, key = (et>>1)*PASSB + dst*2 + (et&1) ----------------
__global__ void count_deg2(const int* __restrict__ dst, const int* __restrict__ et,
                           u32* __restrict__ cnt){
  int e=blockIdx.x*256+threadIdx.x;
  int t=et[e];
  int key=(t>>1)*PASSB + dst[e]*2 + (t&1);
  atomicAdd(&cnt[key],1u);
}

__global__ void scan1(u32* __restrict__ cnt, u32* __restrict__ rp, u32* __restrict__ bsum){
  __shared__ u32 sh[256];
  int t=threadIdx.x; int base=blockIdx.x*256;
  u32 v=cnt[base+t]; sh[t]=v;
  cnt[base+t]=0u;                       // re-zero cur for scatter
  __syncthreads();
  for(int off=1;off<256;off<<=1){
    u32 tv=(t>=off)?sh[t-off]:0u; __syncthreads();
    sh[t]+=tv; __syncthreads();
  }
  rp[base+t]=sh[t]-v;
  if(t==255) bsum[blockIdx.x]=sh[255];
}

__global__ void scan2b(u32* __restrict__ bsum, u32* __restrict__ rp){
  __shared__ u32 sh[256];
  int t=threadIdx.x;
  u32 v0=bsum[t*4+0],v1=bsum[t*4+1],v2=bsum[t*4+2],v3=bsum[t*4+3];
  u32 s=v0+v1+v2+v3;
  sh[t]=s; __syncthreads();
  for(int off=1;off<256;off<<=1){
    u32 tv=(t>=off)?sh[t-off]:0u; __syncthreads();
    sh[t]+=tv; __syncthreads();
  }
  u32 ex=sh[t]-s;
  bsum[t*4+0]=ex; bsum[t*4+1]=ex+v0; bsum[t*4+2]=ex+v0+v1; bsum[t*4+3]=ex+v0+v1+v2;
  if(t==0) rp[NS]=NE;
  if(t==255) bsum[1024]=0u;
}

__global__ void scatter_edges2(const int* __restrict__ src, const int* __restrict__ dst,
                               const int* __restrict__ et, const u32* __restrict__ rp,
                               const u32* __restrict__ bsum,
                               u32* __restrict__ cur, u32* __restrict__ adj){
  int e=blockIdx.x*256+threadIdx.x;
  int t=et[e];
  int d=dst[e];
  int key=(t>>1)*PASSB + d*2 + (t&1);
  u32 pos=atomicAdd(&cur[key],1u);
  u32 val=(u32)src[e] | (((u32)(((t&1)<<6)|(d&63)))<<15);   // src | localrow<<15 (7b)
  adj[rp[key]+bsum[key>>8]+pos]=val;
}

// ---------------- fused_layer: branchless hardware-ds_add_f32 gather ----------------
// 64-dst blocks, 512 thr (8 waves), 2 blocks/CU. Per pass: zero f32 tile -> range-
// sliced gather: per edge {readlane, coalesced dword load, tail-mask via s_cselect
// + v_and (NO branches), 2x asm ds_add_f32 (no-return: no serial FP chain)} ->
// f32->bf16 hi/lo trunc-split conversion -> GEMM 2 rels. Then self-GEMM + epilogue.
// A32 column convention (R6-verified): col c<64 holds x-col 2c (bflo), c>=64 holds
// x-col 2(c-64)+1 (bfhi); the conversion pass re-interleaves to direct layout.
__global__ __launch_bounds__(512,4) void fused_layer(
    const u16* __restrict__ xh, const u16* __restrict__ xl,
    const u16* __restrict__ Bp,
    const u32* __restrict__ rp, const u32* __restrict__ bsum,
    const u32* __restrict__ adj,
    const float* __restrict__ sb, const int* __restrict__ mask,
    u16* __restrict__ oh, u16* __restrict__ ol, float* __restrict__ outf, int last)
{
  __shared__ float A32[128*128];    // 64 KB f32 accum; reused as bf16 hi(32K)+lo(32K)
  __shared__ float sdeg[64];
  u16* As16=(u16*)A32;
  u32* As32w=(u32*)A32;
  const int tid=threadIdx.x;
  const int wave=tid>>6, lane=tid&63;
  const int wm=wave>>2, wn=wave&3;
  const int q=lane>>4;
  const int d0=blockIdx.x*64;
  const u32* xh32=(const u32*)xh;

  f32x4 accR[2][2];
#pragma unroll
  for(int a=0;a<2;a++)
#pragma unroll
    for(int b=0;b<2;b++) accR[a][b]=(f32x4){0.f,0.f,0.f,0.f};

  for(int p=0;p<4;p++){
    // ---- zero f32 tile ----
    { uint4 zz={0u,0u,0u,0u};
#pragma unroll
      for(int k2=0;k2<8;k2++) *(uint4*)&A32[k2*2048+tid*4]=zz;
    }
    __syncthreads();
    // ---- gather: range-sliced, fully branchless, hardware ds_add_f32 ----
    { u32 kb=(u32)(p*PASSB + d0*2);
      u32 ke=kb+128u;
      u32 beg=rp[kb]+bsum[kb>>8];
      u32 end=rp[ke]+bsum[ke>>8];
      u32 len=end-beg;
      u32 wbeg=beg + (len*(u32)wave)/8u;
      u32 wend=beg + (len*(u32)(wave+1))/8u;
      for(u32 base=wbeg; base<wend; base+=64u){
        int nk=(int)(wend-base); if(nk>64) nk=64;
        u32 adjv=(lane<nk)?adj[base+lane]:0u;   // lanes >= nk -> 0 (tail loads x[0])
        u32 hA[16], hB[16];
#pragma unroll
        for(int g=0; g<2; ++g){
          const int b0=g*32;
          // issue 32 loads unguarded (dest regs distinct -> all in flight)
#pragma unroll
          for(int j=0;j<16;j++){
            u32 w=(u32)__builtin_amdgcn_readlane((int)adjv,b0+j);
            hA[j]=xh32[(size_t)(w&0x7fffu)*64+lane];
          }
#pragma unroll
          for(int j=0;j<16;j++){
            u32 w=(u32)__builtin_amdgcn_readlane((int)adjv,b0+16+j);
            hB[j]=xh32[(size_t)(w&0x7fffu)*64+lane];
          }
          // consume: tail-masked (h=0 -> adds +0.0 to row 0, exact no-op)
#pragma unroll
          for(int j=0;j<16;j++){
            u32 w=(u32)__builtin_amdgcn_readlane((int)adjv,b0+j);
            u32 sm=(b0+j<nk)?0xffffffffu:0u;
            u32 h=hA[j]&sm;
            float* rb=&A32[((w>>15)<<7)+lane];
            ds_addf(rb, bflo(h));
            ds_addf_off256(rb, bfhi(h));
          }
#pragma unroll
          for(int j=0;j<16;j++){
            u32 w=(u32)__builtin_amdgcn_readlane((int)adjv,b0+16+j);
            u32 sm=(b0+16+j<nk)?0xffffffffu:0u;
            u32 h=hB[j]&sm;
            float* rb=&A32[((w>>15)<<7)+lane];
            ds_addf(rb, bflo(h));
            ds_addf_off256(rb, bfhi(h));
          }
        }
      }
      asm volatile("s_waitcnt lgkmcnt(0)");
    }
    __syncthreads();
    // ---- conversion: f32 -> bf16 hi/lo (trunc split), read-all then write-all ----
    { float c0[16], c1[16];
#pragma unroll
      for(int r=0;r<16;r++){
        int row=wave*16+r;
        c0[r]=A32[row*128+lane];
        c1[r]=A32[row*128+64+lane];
      }
      __syncthreads();
#pragma unroll
      for(int r=0;r<16;r++){
        int row=wave*16+r;
        u32 u0=__float_as_uint(c0[r]), u1=__float_as_uint(c1[r]);
        u32 hp=(u1&0xffff0000u)|(u0>>16);
        float l0=c0[r]-__uint_as_float(u0&0xffff0000u);
        float l1=c1[r]-__uint_as_float(u1&0xffff0000u);
        u32 lp=(__float_as_uint(l1)&0xffff0000u)|(__float_as_uint(l0)>>16);
        int fw=row*64 + (((lane>>2)^(row&15))<<2) + (lane&3);
        As32w[fw]=hp;
        As32w[8192+fw]=lp;
      }
    }
    __syncthreads();
    // ---- GEMM relations 2p, 2p+1 (2x4 wave tiling) ----
#pragma unroll
    for(int rl=0;rl<2;rl++){
      const u16* Bt=Bp+(size_t)(p*2+rl)*32768;
#pragma unroll
      for(int ks=0;ks<4;ks++){
        bf16x8 ah[2],al[2];
#pragma unroll
        for(int mf=0;mf<2;mf++){
          int ar=rl*64+wm*32+mf*16+(lane&15);
          int off=ar*128+((((ks<<2)+q)^(ar&15))<<3);
          ah[mf]=*(const bf16x8*)&As16[off];
          al[mf]=*(const bf16x8*)&As16[16384+off];
        }
#pragma unroll
        for(int tn=0;tn<2;tn++){
          int n=wn*32+tn*16+(lane&15);
          size_t boff=((size_t)(ks*128+n))*32+q*8;
          bf16x8 bh=*(const bf16x8*)&Bt[boff];
          bf16x8 bl=*(const bf16x8*)&Bt[boff+16384];
#pragma unroll
          for(int mf=0;mf<2;mf++){
            accR[mf][tn]=__builtin_amdgcn_mfma_f32_16x16x32_bf16(ah[mf],bh,accR[mf][tn],0,0,0);
            accR[mf][tn]=__builtin_amdgcn_mfma_f32_16x16x32_bf16(al[mf],bh,accR[mf][tn],0,0,0);
            accR[mf][tn]=__builtin_amdgcn_mfma_f32_16x16x32_bf16(ah[mf],bl,accR[mf][tn],0,0,0);
          }
        }
      }
    }
    __syncthreads();
  }

  // ---- self: stage x rows d0..d0+63 hi/lo into As (linear dest, pre-swz src) ----
#pragma unroll
  for(int i=0;i<2;i++){
    int rbase=wave*8+i*4;
    int r=rbase+(lane>>4);
    int g=(lane&15)^(r&15);
    gl_lds16(xh+(size_t)(d0+r)*HD+g*8, (char*)A32 + rbase*256);
    gl_lds16(xl+(size_t)(d0+r)*HD+g*8, (char*)A32 + 32768 + rbase*256);
  }
  if(tid<64){
    int g=d0+tid; u32 dg=0;
#pragma unroll
    for(int ph=0;ph<4;ph++){
      u32 k=(u32)(ph*PASSB+g*2);
      dg+=(rp[k+2]+bsum[(k+2)>>8])-(rp[k]+bsum[k>>8]);
    }
    sdeg[tid]=1.f/fmaxf((float)dg,1.f);
  }
  __syncthreads();

  f32x4 accS[2][2];
#pragma unroll
  for(int a=0;a<2;a++)
#pragma unroll
    for(int b=0;b<2;b++) accS[a][b]=(f32x4){0.f,0.f,0.f,0.f};
  { const u16* Bt=Bp+(size_t)8*32768;
#pragma unroll
    for(int ks=0;ks<4;ks++){
      bf16x8 ah[2],al[2];
#pragma unroll
      for(int mf=0;mf<2;mf++){
        int ar=wm*32+mf*16+(lane&15);
        int off=ar*128+((((ks<<2)+q)^(ar&15))<<3);
        ah[mf]=*(const bf16x8*)&As16[off];
        al[mf]=*(const bf16x8*)&As16[16384+off];
      }
#pragma unroll
      for(int tn=0;tn<2;tn++){
        int n=wn*32+tn*16+(lane&15);
        size_t boff=((size_t)(ks*128+n))*32+q*8;
        bf16x8 bh=*(const bf16x8*)&Bt[boff];
        bf16x8 bl=*(const bf16x8*)&Bt[boff+16384];
#pragma unroll
        for(int mf=0;mf<2;mf++){
          accS[mf][tn]=__builtin_amdgcn_mfma_f32_16x16x32_bf16(ah[mf],bh,accS[mf][tn],0,0,0);
          accS[mf][tn]=__builtin_amdgcn_mfma_f32_16x16x32_bf16(al[mf],bh,accS[mf][tn],0,0,0);
          accS[mf][tn]=__builtin_amdgcn_mfma_f32_16x16x32_bf16(ah[mf],bl,accS[mf][tn],0,0,0);
        }
      }
    }
  }

  // ---- epilogue: out = relu(accS + sb + accR/deg) ----
#pragma unroll
  for(int tn=0;tn<2;tn++){
    int n=wn*32+tn*16+(lane&15);
    float bb=sb[n];
    if(last){
#pragma unroll
      for(int mf=0;mf<2;mf++)
#pragma unroll
        for(int rr=0;rr<4;rr++){
          int row=wm*32+mf*16+q*4+rr;
          float v=fmaxf(accS[mf][tn][rr]+bb+accR[mf][tn][rr]*sdeg[row],0.f);
          v*=(float)mask[d0+row];
          outf[(size_t)(d0+row)*HD+n]=v;
        }
    } else {
#pragma unroll
      for(int mf=0;mf<2;mf++)
#pragma unroll
        for(int rr=0;rr<4;rr++){
          int row=wm*32+mf*16+q*4+rr;
          float v=fmaxf(accS[mf][tn][rr]+bb+accR[mf][tn][rr]*sdeg[row],0.f);
          u16 hb=f2bf(v);
          u16 lb=f2bf(v-bf2f(hb));
          oh[(size_t)(d0+row)*HD+n]=hb;
          ol[(size_t)(d0+row)*HD+n]=lb;
        }
    }
  }
}

extern "C" void kernel_launch(void* const* d_in, const int* in_sizes, int n_in,
                              void* d_out, int out_size, void* d_ws, size_t ws_size,
                              hipStream_t stream)
{
  (void)in_sizes; (void)n_in; (void)out_size; (void)ws_size;
  const int*   cid =(const int*)  d_in[0];
  const int*   kid =(const int*)  d_in[1];
  const int*   mask=(const int*)  d_in[2];
  const int*   ei  =(const int*)  d_in[3];
  const int*   et  =(const int*)  d_in[4];
  const float* cemb=(const float*)d_in[5];
  const float* kemb=(const float*)d_in[6];
  const float* pW  =(const float*)d_in[7];
  const float* pb  =(const float*)d_in[8];
  const float* sW  =(const float*)d_in[9];
  const float* sb  =(const float*)d_in[10];
  const float* rW  =(const float*)d_in[11];
  float* out=(float*)d_out;
  char*  ws =(char*)d_ws;

  u16* xh =(u16*)(ws+XH_OFF);
  u16* xl =(u16*)(ws+XL_OFF);
  u16* xh2=(u16*)(ws+XH2_OFF);
  u16* xl2=(u16*)(ws+XL2_OFF);
  u32* adj =(u32*)(ws+ADJ_OFF);
  u32* rp  =(u32*)(ws+RP_OFF);
  u32* cur =(u32*)(ws+CUR_OFF);
  u32* bsum=(u32*)(ws+BSUM_OFF);
  u16* Bp  =(u16*)(ws+BP_OFF);
  const int* srcA=ei;
  const int* dstA=ei+NE;

  hipMemsetAsync(cur,0,NS*sizeof(u32),stream);
  prep_w<<<1216,256,0,stream>>>(rW,sW,pW,Bp);
  embed_mfma<<<NODES/128,256,0,stream>>>(cid,kid,cemb,kemb,Bp+PP_ELEM,pb,xh,xl);
  count_deg2<<<NE/256,256,0,stream>>>(dstA,et,cur);
  scan1<<<NS/256,256,0,stream>>>(cur,rp,bsum);
  scan2b<<<1,256,0,stream>>>(bsum,rp);
  scatter_edges2<<<NE/256,256,0,stream>>>(srcA,dstA,et,rp,bsum,cur,adj);

  fused_layer<<<NODES/64,512,0,stream>>>(xh,xl,Bp,rp,bsum,adj,sb,mask,xh2,xl2,out,0);
  fused_layer<<<NODES/64,512,0,stream>>>(xh2,xl2,Bp+BP_LAYER,rp,bsum,adj,sb+HD,mask,xh,xl,out,1);
}

// Round 9
// 403.381 us; speedup vs baseline: 3.9269x; 3.9269x over previous
//
#include <hip/hip_runtime.h>
#include <hip/hip_bf16.h>

#define NODES 32768
#define HD 128
#define NE 524288
#define NR 8
#define NS 262144                          // 8 rels * NODES keys (rel-major)

typedef unsigned int u32;
typedef unsigned short u16;
typedef __attribute__((ext_vector_type(8))) short bf16x8;
typedef __attribute__((ext_vector_type(4))) float f32x4;

// ---- ws byte offsets ----
#define XH_OFF   (0u)                      // bf16 hi x, 8 MB
#define XL_OFF   (8u<<20)                  // bf16 lo x, 8 MB
#define XH2_OFF  (16u<<20)                 // layer-1 x hi
#define XL2_OFF  (24u<<20)                 // layer-1 x lo
#define ADJ_OFF  (32u<<20)                 // u32 x NE packed (src | localdst<<15)
#define RP_OFF   (34u<<20)                 // u32 x (NS+1)
#define CUR_OFF  (36u<<20)                 // u32 x NS
#define BSUM_OFF (37u<<20)                 // u32 x 1025
#define BP_OFF   (38u<<20)                 // packed weights bf16

#define BP_LAYER 294912                    // 9*2*16384
#define PP_ELEM  589824                    // pW packed at Bp+PP_ELEM

__device__ __forceinline__ float bflo(u32 u){ union{u32 i;float f;}c; c.i=u<<16; return c.f; }
__device__ __forceinline__ float bfhi(u32 u){ union{u32 i;float f;}c; c.i=u&0xffff0000u; return c.f; }
__device__ __forceinline__ u16 f2bf(float f){
  u32 u=__float_as_uint(f);
  u32 r=u + 0x7fffu + ((u>>16)&1u);
  return (u16)(r>>16);
}
__device__ __forceinline__ float bf2f(u16 h){ return __uint_as_float(((u32)h)<<16); }

__device__ __forceinline__ void gl_lds16(const void* g, void* l){
  __builtin_amdgcn_global_load_lds((const __attribute__((address_space(1))) u32*)g,
                                   (__attribute__((address_space(3))) u32*)l, 16, 0, 0);
}

// ---------------- weight prep: 2 layers x 9 tiles (8 rel + self) + pW, hi/lo segs ----
__global__ void prep_w(const float* __restrict__ rW, const float* __restrict__ sW,
                       const float* __restrict__ pWg, u16* __restrict__ Bp)
{
  int idx=blockIdx.x*256+threadIdx.x;           // 311296 total
  if(idx<294912){
    int l=idx/147456;
    int rem=idx%147456;
    int t=rem>>14;
    int kn=rem&16383;
    int k=kn>>7, n=kn&127;
    float w;
    if(t<8) w=rW[(((size_t)l*NR+t)*HD+n)*HD+k];
    else    w=sW[((size_t)l*HD+n)*HD+k];
    u16* base=Bp+(size_t)l*BP_LAYER+(size_t)t*32768;
    int ks=k>>5, q=(k>>3)&3, j=k&7;
    size_t off=((size_t)ks*128+n)*32+q*8+j;
    u16 hb=f2bf(w);
    u16 lb=f2bf(w-bf2f(hb));
    base[off]=hb;
    base[off+16384]=lb;
  } else {
    int kn=idx-294912;
    int k=kn>>7, n=kn&127;
    float w=pWg[(size_t)n*HD+k];
    u16* base=Bp+PP_ELEM;
    int ks=k>>5, q=(k>>3)&3, j=k&7;
    size_t off=((size_t)ks*128+n)*32+q*8+j;
    u16 hb=f2bf(w);
    u16 lb=f2bf(w-bf2f(hb));
    base[off]=hb;
    base[off+16384]=lb;
  }
}

// ---------------- embed_mfma: x = (cemb[cid]+kemb[kid]) @ pW^T + pb -> xh/xl ----------
__global__ __launch_bounds__(256,2) void embed_mfma(
    const int* __restrict__ cid, const int* __restrict__ kid,
    const float* __restrict__ cemb, const float* __restrict__ kemb,
    const u16* __restrict__ PP, const float* __restrict__ pb,
    u16* __restrict__ xh, u16* __restrict__ xl)
{
  __shared__ u16 Atile[2][128*128];   // [0]=hi [1]=lo, 64 KB, XOR-16 swizzle
  const int tid=threadIdx.x;
  const int wave=tid>>6, lane=tid&63;
  const int wm=wave>>1, wn=wave&1;
  const int q=lane>>4;
  const int d0=blockIdx.x*128;

  { int r=tid>>1, half=tid&1;
    int ci=cid[d0+r], ki=kid[d0+r];
    const float* cp=cemb+(size_t)ci*HD+half*64;
    const float* kp=kemb+(size_t)ki*HD+half*64;
#pragma unroll
    for(int cc=0;cc<8;cc++){
      float4 a0=*(const float4*)(cp+cc*8);
      float4 a1=*(const float4*)(cp+cc*8+4);
      float4 b0=*(const float4*)(kp+cc*8);
      float4 b1=*(const float4*)(kp+cc*8+4);
      float v[8]={a0.x+b0.x,a0.y+b0.y,a0.z+b0.z,a0.w+b0.w,
                  a1.x+b1.x,a1.y+b1.y,a1.z+b1.z,a1.w+b1.w};
      u16 hb[8], lb[8];
#pragma unroll
      for(int j=0;j<8;j++){ hb[j]=f2bf(v[j]); lb[j]=f2bf(v[j]-bf2f(hb[j])); }
      int chunk=half*8+cc;
      int dst=r*128+(chunk^(r&15))*8;
      uint4 hv={(u32)hb[0]|((u32)hb[1]<<16),(u32)hb[2]|((u32)hb[3]<<16),
                (u32)hb[4]|((u32)hb[5]<<16),(u32)hb[6]|((u32)hb[7]<<16)};
      uint4 lv={(u32)lb[0]|((u32)lb[1]<<16),(u32)lb[2]|((u32)lb[3]<<16),
                (u32)lb[4]|((u32)lb[5]<<16),(u32)lb[6]|((u32)lb[7]<<16)};
      *(uint4*)&Atile[0][dst]=hv;
      *(uint4*)&Atile[1][dst]=lv;
    }
  }
  __syncthreads();

  f32x4 acc[4][4];
#pragma unroll
  for(int a=0;a<4;a++)
#pragma unroll
    for(int b=0;b<4;b++) acc[a][b]=(f32x4){0.f,0.f,0.f,0.f};

#pragma unroll
  for(int ks=0;ks<4;ks++){
    bf16x8 ah[4];
#pragma unroll
    for(int tm=0;tm<4;tm++){
      int m=wm*64+tm*16+(lane&15);
      ah[tm]=*(const bf16x8*)&Atile[0][m*128+(((ks*4)+q)^(m&15))*8];
    }
#pragma unroll
    for(int s=0;s<2;s++){
      const u16* Bb=PP+s*16384;
#pragma unroll
      for(int tn=0;tn<4;tn++){
        int n=wn*64+tn*16+(lane&15);
        bf16x8 bfr=*(const bf16x8*)&Bb[((size_t)ks*128+n)*32+q*8];
#pragma unroll
        for(int tm=0;tm<4;tm++)
          acc[tm][tn]=__builtin_amdgcn_mfma_f32_16x16x32_bf16(ah[tm],bfr,acc[tm][tn],0,0,0);
      }
    }
  }
#pragma unroll
  for(int ks=0;ks<4;ks++){
    bf16x8 al[4];
#pragma unroll
    for(int tm=0;tm<4;tm++){
      int m=wm*64+tm*16+(lane&15);
      al[tm]=*(const bf16x8*)&Atile[1][m*128+(((ks*4)+q)^(m&15))*8];
    }
#pragma unroll
    for(int tn=0;tn<4;tn++){
      int n=wn*64+tn*16+(lane&15);
      bf16x8 bfr=*(const bf16x8*)&PP[((size_t)ks*128+n)*32+q*8];
#pragma unroll
      for(int tm=0;tm<4;tm++)
        acc[tm][tn]=__builtin_amdgcn_mfma_f32_16x16x32_bf16(al[tm],bfr,acc[tm][tn],0,0,0);
    }
  }

  // ---- epilogue: +pb, hi/lo split into dead Atile (swz bits5-6), linear dwordx4 out ----
  __syncthreads();
  { u16* Sh=(u16*)Atile[0];
    u16* Sl=(u16*)Atile[1];
#pragma unroll
    for(int tn=0;tn<4;tn++){
      int n=wn*64+tn*16+(lane&15);
      float b=pb[n];
#pragma unroll
      for(int tm=0;tm<4;tm++){
        int rbase=wm*64+tm*16+q*4;
#pragma unroll
        for(int r=0;r<4;r++){
          float v=acc[tm][tn][r]+b;
          u16 hb=f2bf(v);
          u16 lb=f2bf(v-bf2f(hb));
          int row=rbase+r;
          u32 ab=(u32)(row*256+n*2);
          ab^=((u32)((row>>2)&3))<<5;
          Sh[ab>>1]=hb;
          Sl[ab>>1]=lb;
        }
      }
    }
  }
  __syncthreads();
  { const char* S0=(const char*)Atile[0];
    const char* S1=(const char*)Atile[1];
    char* xhb=(char*)(xh+(size_t)d0*HD);
    char* xlb=(char*)(xl+(size_t)d0*HD);
#pragma unroll
    for(int i=0;i<8;i++){
      u32 byte=(u32)(i*256+tid)*16;       // 32 KB tile, 16 lanes = one 256B row
      u32 row=byte>>8;
      u32 lb2=byte^((((row>>2)&3))<<5);
      *(uint4*)(xhb+byte)=*(const uint4*)(S0+lb2);
      *(uint4*)(xlb+byte)=*(const uint4*)(S1+lb2);
    }
  }
}

// ---------------- CSR build, key = et*NODES + dst (rel-major passes) ----------------
__global__ void count_deg2(const int* __restrict__ dst, const int* __restrict__ et,
                           u32* __restrict__ cnt){
  int e=blockIdx.x*256+threadIdx.x;
  int key=et[e]*NODES + dst[e];
  atomicAdd(&cnt[key],1u);
}

__global__ void scan1(u32* __restrict__ cnt, u32* __restrict__ rp, u32* __restrict__ bsum){
  __shared__ u32 sh[256];
  int t=threadIdx.x; int base=blockIdx.x*256;
  u32 v=cnt[base+t]; sh[t]=v;
  cnt[base+t]=0u;                       // re-zero cur for scatter
  __syncthreads();
  for(int off=1;off<256;off<<=1){
    u32 tv=(t>=off)?sh[t-off]:0u; __syncthreads();
    sh[t]+=tv; __syncthreads();
  }
  rp[base+t]=sh[t]-v;
  if(t==255) bsum[blockIdx.x]=sh[255];
}

__global__ void scan2b(u32* __restrict__ bsum, u32* __restrict__ rp){
  __shared__ u32 sh[256];
  int t=threadIdx.x;
  u32 v0=bsum[t*4+0],v1=bsum[t*4+1],v2=bsum[t*4+2],v3=bsum[t*4+3];
  u32 s=v0+v1+v2+v3;
  sh[t]=s; __syncthreads();
  for(int off=1;off<256;off<<=1){
    u32 tv=(t>=off)?sh[t-off]:0u; __syncthreads();
    sh[t]+=tv; __syncthreads();
  }
  u32 ex=sh[t]-s;
  bsum[t*4+0]=ex; bsum[t*4+1]=ex+v0; bsum[t*4+2]=ex+v0+v1; bsum[t*4+3]=ex+v0+v1+v2;
  if(t==0) rp[NS]=NE;
  if(t==255) bsum[1024]=0u;
}

__global__ void scatter_edges2(const int* __restrict__ src, const int* __restrict__ dst,
                               const int* __restrict__ et, const u32* __restrict__ rp,
                               const u32* __restrict__ bsum,
                               u32* __restrict__ cur, u32* __restrict__ adj){
  int e=blockIdx.x*256+threadIdx.x;
  int d=dst[e];
  int key=et[e]*NODES + d;
  u32 pos=atomicAdd(&cur[key],1u);
  adj[rp[key]+bsum[key>>8]+pos]=(u32)src[e] | (((u32)(d&63))<<15);  // src | localdst<<15
}

// ---------------- fused_layer v4: branch-free register gather (uniform-select FMA) ----
// 64-dst blocks, 512 thr (8 waves), 2 blocks/CU, LDS 32 KB.
// 8 rel-pure passes. Per pass: each wave owns 8 dsts (= 8 register rows v0/v1,
// compile-time indexed). Per edge: readlane (SALU) -> coalesced dword load ->
// 8x { scalar ind=(row==c)?1:0 (s_cmp+s_cselect, row is wave-uniform) -> 2 v_fmac }.
// NO branches, NO atomics, NO LDS in the hot loop -> 32-deep load batch pipelines.
// Flush: trunc hi per row into swizzled As (rows self-zero via flush; no memset).
// Rel-GEMM hi-only A,B (R7-verified numerics); self-GEMM full hi/lo.
__global__ __launch_bounds__(512,2) void fused_layer(
    const u16* __restrict__ xh, const u16* __restrict__ xl,
    const u16* __restrict__ Bp,
    const u32* __restrict__ rp, const u32* __restrict__ bsum,
    const u32* __restrict__ adj,
    const float* __restrict__ sb, const int* __restrict__ mask,
    u16* __restrict__ oh, u16* __restrict__ ol, float* __restrict__ outf, int last)
{
  __shared__ u32 As32w[8192];       // 32 KB: hi plane words 0..4095, lo plane 4096..8191
  __shared__ float sdeg[64];
  u16* As16=(u16*)As32w;
  const int tid=threadIdx.x;
  const int wave=tid>>6, lane=tid&63;
  const int wm=wave>>2, wn=wave&3;
  const int q=lane>>4;
  const int d0=blockIdx.x*64;
  const u32* xh32=(const u32*)xh;

  f32x4 accR[2][2];
#pragma unroll
  for(int a=0;a<2;a++)
#pragma unroll
    for(int b=0;b<2;b++) accR[a][b]=(f32x4){0.f,0.f,0.f,0.f};

  for(int p=0;p<8;p++){
    // ---- gather: wave's 8 contiguous keys (8 dsts, rel p), register rows ----
    float v0[8], v1[8];
#pragma unroll
    for(int r=0;r<8;r++){ v0[r]=0.f; v1[r]=0.f; }
    { u32 kb=(u32)(p*NODES + d0 + wave*8);
      u32 beg=rp[kb]+bsum[kb>>8];
      u32 ke=kb+8u;
      u32 end=rp[ke]+bsum[ke>>8];
      for(u32 base=beg; base<end; base+=32u){
        int nk=(int)(end-base); if(nk>32) nk=32;
        u32 adjv=(lane<nk)?adj[base+lane]:0u;   // lanes >= nk -> 0 (tail loads x[0])
        u32 h[32];
#pragma unroll
        for(int j=0;j<32;j++){
          u32 w=(u32)__builtin_amdgcn_readlane((int)adjv,j);
          h[j]=xh32[(size_t)(w&0x7fffu)*64+lane];
        }
#pragma unroll
        for(int j=0;j<32;j++){
          u32 w=(u32)__builtin_amdgcn_readlane((int)adjv,j);
          int row=(int)(w>>15);                  // wave-uniform (SGPR), 0..63
          u32 sm=(j<nk)?0xffffffffu:0u;          // scalar select
          u32 hm=h[j]&sm;
          float fl=bflo(hm), fh=bfhi(hm);
#pragma unroll
          for(int r=0;r<8;r++){
            float ind=(row==(wave*8+r))?1.0f:0.0f;   // s_cmp + s_cselect
            v0[r]=__builtin_fmaf(ind,fl,v0[r]);       // v_fmac with SGPR ind
            v1[r]=__builtin_fmaf(ind,fh,v1[r]);
          }
        }
      }
    }
    // ---- flush: hi-only trunc per row into swizzled As (writes ALL 64 rows) ----
#pragma unroll
    for(int r=0;r<8;r++){
      int row=wave*8+r;
      u32 u0=__float_as_uint(v0[r]), u1=__float_as_uint(v1[r]);
      u32 hp=(u1&0xffff0000u)|(u0>>16);
      int fw=row*64+(((lane>>2)^(row&15))<<2)+(lane&3);
      As32w[fw]=hp;
    }
    __syncthreads();
    // ---- rel-GEMM: single-plane A x single-plane B (hi), accumulate over passes ----
    { const u16* Bt=Bp+(size_t)p*32768;
#pragma unroll
      for(int ks=0;ks<4;ks++){
        bf16x8 ah[2];
#pragma unroll
        for(int mf=0;mf<2;mf++){
          int ar=wm*32+mf*16+(lane&15);
          ah[mf]=*(const bf16x8*)&As16[ar*128+((((ks<<2)+q)^(ar&15))<<3)];
        }
#pragma unroll
        for(int tn=0;tn<2;tn++){
          int n=wn*32+tn*16+(lane&15);
          bf16x8 bh=*(const bf16x8*)&Bt[((size_t)(ks*128+n))*32+q*8];
#pragma unroll
          for(int mf=0;mf<2;mf++)
            accR[mf][tn]=__builtin_amdgcn_mfma_f32_16x16x32_bf16(ah[mf],bh,accR[mf][tn],0,0,0);
        }
      }
    }
    __syncthreads();
  }

  // ---- self: stage x rows d0..d0+63 hi plane @0, lo plane @16KB; deg ----
#pragma unroll
  for(int i=0;i<2;i++){
    int rbase=wave*8+i*4;
    int r=rbase+(lane>>4);
    int g=(lane&15)^(r&15);
    gl_lds16(xh+(size_t)(d0+r)*HD+g*8, (char*)As32w + rbase*256);
    gl_lds16(xl+(size_t)(d0+r)*HD+g*8, (char*)As32w + 16384 + rbase*256);
  }
  if(tid<64){
    int g=d0+tid; u32 dg=0;
#pragma unroll
    for(int ph=0;ph<8;ph++){
      u32 k=(u32)(ph*NODES+g);
      dg+=(rp[k+1]+bsum[(k+1)>>8])-(rp[k]+bsum[k>>8]);
    }
    sdeg[tid]=1.f/fmaxf((float)dg,1.f);
  }
  __syncthreads();

  // ---- self-GEMM: full hi/lo A x hi/lo B ----
  f32x4 accS[2][2];
#pragma unroll
  for(int a=0;a<2;a++)
#pragma unroll
    for(int b=0;b<2;b++) accS[a][b]=(f32x4){0.f,0.f,0.f,0.f};
  { const u16* Bt=Bp+(size_t)8*32768;
#pragma unroll
    for(int ks=0;ks<4;ks++){
      bf16x8 ah[2],al[2];
#pragma unroll
      for(int mf=0;mf<2;mf++){
        int ar=wm*32+mf*16+(lane&15);
        int off=ar*128+((((ks<<2)+q)^(ar&15))<<3);
        ah[mf]=*(const bf16x8*)&As16[off];
        al[mf]=*(const bf16x8*)&As16[8192+off];
      }
#pragma unroll
      for(int tn=0;tn<2;tn++){
        int n=wn*32+tn*16+(lane&15);
        size_t boff=((size_t)(ks*128+n))*32+q*8;
        bf16x8 bh=*(const bf16x8*)&Bt[boff];
        bf16x8 bl=*(const bf16x8*)&Bt[boff+16384];
#pragma unroll
        for(int mf=0;mf<2;mf++){
          accS[mf][tn]=__builtin_amdgcn_mfma_f32_16x16x32_bf16(ah[mf],bh,accS[mf][tn],0,0,0);
          accS[mf][tn]=__builtin_amdgcn_mfma_f32_16x16x32_bf16(al[mf],bh,accS[mf][tn],0,0,0);
          accS[mf][tn]=__builtin_amdgcn_mfma_f32_16x16x32_bf16(ah[mf],bl,accS[mf][tn],0,0,0);
        }
      }
    }
  }

  // ---- epilogue: out = relu(accS + sb + accR/deg); C/D: col=lane&15, row=q*4+reg ----
#pragma unroll
  for(int tn=0;tn<2;tn++){
    int n=wn*32+tn*16+(lane&15);
    float bb=sb[n];
    if(last){
#pragma unroll
      for(int mf=0;mf<2;mf++)
#pragma unroll
        for(int rr=0;rr<4;rr++){
          int row=wm*32+mf*16+q*4+rr;
          float v=fmaxf(accS[mf][tn][rr]+bb+accR[mf][tn][rr]*sdeg[row],0.f);
          v*=(float)mask[d0+row];
          outf[(size_t)(d0+row)*HD+n]=v;
        }
    } else {
#pragma unroll
      for(int mf=0;mf<2;mf++)
#pragma unroll
        for(int rr=0;rr<4;rr++){
          int row=wm*32+mf*16+q*4+rr;
          float v=fmaxf(accS[mf][tn][rr]+bb+accR[mf][tn][rr]*sdeg[row],0.f);
          u16 hb=f2bf(v);
          u16 lb=f2bf(v-bf2f(hb));
          oh[(size_t)(d0+row)*HD+n]=hb;
          ol[(size_t)(d0+row)*HD+n]=lb;
        }
    }
  }
}

extern "C" void kernel_launch(void* const* d_in, const int* in_sizes, int n_in,
                              void* d_out, int out_size, void* d_ws, size_t ws_size,
                              hipStream_t stream)
{
  (void)in_sizes; (void)n_in; (void)out_size; (void)ws_size;
  const int*   cid =(const int*)  d_in[0];
  const int*   kid =(const int*)  d_in[1];
  const int*   mask=(const int*)  d_in[2];
  const int*   ei  =(const int*)  d_in[3];
  const int*   et  =(const int*)  d_in[4];
  const float* cemb=(const float*)d_in[5];
  const float* kemb=(const float*)d_in[6];
  const float* pW  =(const float*)d_in[7];
  const float* pb  =(const float*)d_in[8];
  const float* sW  =(const float*)d_in[9];
  const float* sb  =(const float*)d_in[10];
  const float* rW  =(const float*)d_in[11];
  float* out=(float*)d_out;
  char*  ws =(char*)d_ws;

  u16* xh =(u16*)(ws+XH_OFF);
  u16* xl =(u16*)(ws+XL_OFF);
  u16* xh2=(u16*)(ws+XH2_OFF);
  u16* xl2=(u16*)(ws+XL2_OFF);
  u32* adj =(u32*)(ws+ADJ_OFF);
  u32* rp  =(u32*)(ws+RP_OFF);
  u32* cur =(u32*)(ws+CUR_OFF);
  u32* bsum=(u32*)(ws+BSUM_OFF);
  u16* Bp  =(u16*)(ws+BP_OFF);
  const int* srcA=ei;
  const int* dstA=ei+NE;

  hipMemsetAsync(cur,0,NS*sizeof(u32),stream);
  prep_w<<<1216,256,0,stream>>>(rW,sW,pW,Bp);
  embed_mfma<<<NODES/128,256,0,stream>>>(cid,kid,cemb,kemb,Bp+PP_ELEM,pb,xh,xl);
  count_deg2<<<NE/256,256,0,stream>>>(dstA,et,cur);
  scan1<<<NS/256,256,0,stream>>>(cur,rp,bsum);
  scan2b<<<1,256,0,stream>>>(bsum,rp);
  scatter_edges2<<<NE/256,256,0,stream>>>(srcA,dstA,et,rp,bsum,cur,adj);

  fused_layer<<<NODES/64,512,0,stream>>>(xh,xl,Bp,rp,bsum,adj,sb,mask,xh2,xl2,out,0);
  fused_layer<<<NODES/64,512,0,stream>>>(xh2,xl2,Bp+BP_LAYER,rp,bsum,adj,sb+HD,mask,xh,xl,out,1);
}

// Round 10
// 373.338 us; speedup vs baseline: 4.2429x; 1.0805x over previous
//
#include <hip/hip_runtime.h>
#include <hip/hip_bf16.h>

#define NODES 32768
#define HD 128
#define NE 524288
#define NR 8
#define NS 262144                          // 4 pass-halves * NODES * 2 keys
#define PASSB 65536                        // keys per pass = NODES*2

typedef unsigned int u32;
typedef unsigned short u16;
typedef __attribute__((ext_vector_type(8))) short bf16x8;
typedef __attribute__((ext_vector_type(4))) float f32x4;

// ---- ws byte offsets ----
#define XH_OFF   (0u)                      // bf16 hi x, 8 MB
#define XL_OFF   (8u<<20)                  // bf16 lo x, 8 MB
#define XH2_OFF  (16u<<20)                 // layer-1 x hi
#define XL2_OFF  (24u<<20)                 // layer-1 x lo
#define ADJ_OFF  (32u<<20)                 // u32 x NE packed (src | row<<15)
#define RP_OFF   (34u<<20)                 // u32 x (NS+1)
#define CUR_OFF  (36u<<20)                 // u32 x NS
#define BSUM_OFF (37u<<20)                 // u32 x 1025
#define BP_OFF   (38u<<20)                 // packed weights bf16

#define BP_LAYER 294912                    // 9*2*16384
#define PP_ELEM  589824                    // pW packed at Bp+PP_ELEM

__device__ __forceinline__ float bflo(u32 u){ union{u32 i;float f;}c; c.i=u<<16; return c.f; }
__device__ __forceinline__ float bfhi(u32 u){ union{u32 i;float f;}c; c.i=u&0xffff0000u; return c.f; }
__device__ __forceinline__ u16 f2bf(float f){
  u32 u=__float_as_uint(f);
  u32 r=u + 0x7fffu + ((u>>16)&1u);
  return (u16)(r>>16);
}
__device__ __forceinline__ float bf2f(u16 h){ return __uint_as_float(((u32)h)<<16); }

__device__ __forceinline__ void gl_lds16(const void* g, void* l){
  __builtin_amdgcn_global_load_lds((const __attribute__((address_space(1))) u32*)g,
                                   (__attribute__((address_space(3))) u32*)l, 16, 0, 0);
}

// ---------------- weight prep: 2 layers x 9 tiles (8 rel + self) + pW, hi/lo segs ----
__global__ void prep_w(const float* __restrict__ rW, const float* __restrict__ sW,
                       const float* __restrict__ pWg, u16* __restrict__ Bp)
{
  int idx=blockIdx.x*256+threadIdx.x;           // 311296 total
  if(idx<294912){
    int l=idx/147456;
    int rem=idx%147456;
    int t=rem>>14;
    int kn=rem&16383;
    int k=kn>>7, n=kn&127;
    float w;
    if(t<8) w=rW[(((size_t)l*NR+t)*HD+n)*HD+k];
    else    w=sW[((size_t)l*HD+n)*HD+k];
    u16* base=Bp+(size_t)l*BP_LAYER+(size_t)t*32768;
    int ks=k>>5, q=(k>>3)&3, j=k&7;
    size_t off=((size_t)ks*128+n)*32+q*8+j;
    u16 hb=f2bf(w);
    u16 lb=f2bf(w-bf2f(hb));
    base[off]=hb;
    base[off+16384]=lb;
  } else {
    int kn=idx-294912;
    int k=kn>>7, n=kn&127;
    float w=pWg[(size_t)n*HD+k];
    u16* base=Bp+PP_ELEM;
    int ks=k>>5, q=(k>>3)&3, j=k&7;
    size_t off=((size_t)ks*128+n)*32+q*8+j;
    u16 hb=f2bf(w);
    u16 lb=f2bf(w-bf2f(hb));
    base[off]=hb;
    base[off+16384]=lb;
  }
}

// ---------------- embed_mfma: 64-row tiles for 2x CU coverage (latency-bound gather) --
__global__ __launch_bounds__(256,4) void embed_mfma(
    const int* __restrict__ cid, const int* __restrict__ kid,
    const float* __restrict__ cemb, const float* __restrict__ kemb,
    const u16* __restrict__ PP, const float* __restrict__ pb,
    u16* __restrict__ xh, u16* __restrict__ xl)
{
  __shared__ u16 Atile[2][64*128];    // [0]=hi [1]=lo, 32 KB, XOR-16 swizzle
  const int tid=threadIdx.x;
  const int wave=tid>>6, lane=tid&63;
  const int wm=wave>>1, wn=wave&1;
  const int q=lane>>4;
  const int d0=blockIdx.x*64;

  // ---- gather + add + split + LDS write: thread = (row=tid>>2, quarter=tid&3) ----
  { int r=tid>>2, q4=tid&3;
    int ci=cid[d0+r], ki=kid[d0+r];
    const float* cp=cemb+(size_t)ci*HD+q4*32;
    const float* kp=kemb+(size_t)ki*HD+q4*32;
#pragma unroll
    for(int cc=0;cc<4;cc++){
      float4 a0=*(const float4*)(cp+cc*8);
      float4 a1=*(const float4*)(cp+cc*8+4);
      float4 b0=*(const float4*)(kp+cc*8);
      float4 b1=*(const float4*)(kp+cc*8+4);
      float v[8]={a0.x+b0.x,a0.y+b0.y,a0.z+b0.z,a0.w+b0.w,
                  a1.x+b1.x,a1.y+b1.y,a1.z+b1.z,a1.w+b1.w};
      u16 hb[8], lb[8];
#pragma unroll
      for(int j=0;j<8;j++){ hb[j]=f2bf(v[j]); lb[j]=f2bf(v[j]-bf2f(hb[j])); }
      int chunk=q4*4+cc;
      int dst=r*128+(chunk^(r&15))*8;
      uint4 hv={(u32)hb[0]|((u32)hb[1]<<16),(u32)hb[2]|((u32)hb[3]<<16),
                (u32)hb[4]|((u32)hb[5]<<16),(u32)hb[6]|((u32)hb[7]<<16)};
      uint4 lv={(u32)lb[0]|((u32)lb[1]<<16),(u32)lb[2]|((u32)lb[3]<<16),
                (u32)lb[4]|((u32)lb[5]<<16),(u32)lb[6]|((u32)lb[7]<<16)};
      *(uint4*)&Atile[0][dst]=hv;
      *(uint4*)&Atile[1][dst]=lv;
    }
  }
  __syncthreads();

  f32x4 acc[2][4];
#pragma unroll
  for(int a=0;a<2;a++)
#pragma unroll
    for(int b=0;b<4;b++) acc[a][b]=(f32x4){0.f,0.f,0.f,0.f};

  // part 0: hi @ {Whi, Wlo}
#pragma unroll
  for(int ks=0;ks<4;ks++){
    bf16x8 ah[2];
#pragma unroll
    for(int tm=0;tm<2;tm++){
      int m=wm*32+tm*16+(lane&15);
      ah[tm]=*(const bf16x8*)&Atile[0][m*128+(((ks*4)+q)^(m&15))*8];
    }
#pragma unroll
    for(int s=0;s<2;s++){
      const u16* Bb=PP+s*16384;
#pragma unroll
      for(int tn=0;tn<4;tn++){
        int n=wn*64+tn*16+(lane&15);
        bf16x8 bfr=*(const bf16x8*)&Bb[((size_t)ks*128+n)*32+q*8];
#pragma unroll
        for(int tm=0;tm<2;tm++)
          acc[tm][tn]=__builtin_amdgcn_mfma_f32_16x16x32_bf16(ah[tm],bfr,acc[tm][tn],0,0,0);
      }
    }
  }
  // part 1: lo @ Whi
#pragma unroll
  for(int ks=0;ks<4;ks++){
    bf16x8 al[2];
#pragma unroll
    for(int tm=0;tm<2;tm++){
      int m=wm*32+tm*16+(lane&15);
      al[tm]=*(const bf16x8*)&Atile[1][m*128+(((ks*4)+q)^(m&15))*8];
    }
#pragma unroll
    for(int tn=0;tn<4;tn++){
      int n=wn*64+tn*16+(lane&15);
      bf16x8 bfr=*(const bf16x8*)&PP[((size_t)ks*128+n)*32+q*8];
#pragma unroll
      for(int tm=0;tm<2;tm++)
        acc[tm][tn]=__builtin_amdgcn_mfma_f32_16x16x32_bf16(al[tm],bfr,acc[tm][tn],0,0,0);
    }
  }

  // ---- epilogue: +pb, hi/lo split into dead Atile (swz bits5-6), linear dwordx4 out ----
  __syncthreads();
  { u16* Sh=(u16*)Atile[0];
    u16* Sl=(u16*)Atile[1];
#pragma unroll
    for(int tn=0;tn<4;tn++){
      int n=wn*64+tn*16+(lane&15);
      float b=pb[n];
#pragma unroll
      for(int tm=0;tm<2;tm++){
        int rbase=wm*32+tm*16+q*4;
#pragma unroll
        for(int r=0;r<4;r++){
          float v=acc[tm][tn][r]+b;
          u16 hb=f2bf(v);
          u16 lb=f2bf(v-bf2f(hb));
          int row=rbase+r;
          u32 ab=(u32)(row*256+n*2);
          ab^=((u32)((row>>2)&3))<<5;
          Sh[ab>>1]=hb;
          Sl[ab>>1]=lb;
        }
      }
    }
  }
  __syncthreads();
  { const char* S0=(const char*)Atile[0];
    const char* S1=(const char*)Atile[1];
    char* xhb=(char*)(xh+(size_t)d0*HD);
    char* xlb=(char*)(xl+(size_t)d0*HD);
#pragma unroll
    for(int i=0;i<4;i++){
      u32 byte=(u32)(i*256+tid)*16;       // 16 KB per plane
      u32 row=byte>>8;
      u32 lb2=byte^((((row>>2)&3))<<5);
      *(uint4*)(xhb+byte)=*(const uint4*)(S0+lb2);
      *(uint4*)(xlb+byte)=*(const uint4*)(S1+lb2);
    }
  }
}

// ---------------- CSR build, key = (et>>1)*PASSB + dst*2 + (et&1) ----------------
__global__ void count_deg2(const int* __restrict__ dst, const int* __restrict__ et,
                           u32* __restrict__ cnt){
  int e=blockIdx.x*256+threadIdx.x;
  int t=et[e];
  int key=(t>>1)*PASSB + dst[e]*2 + (t&1);
  atomicAdd(&cnt[key],1u);
}

__global__ void scan1(u32* __restrict__ cnt, u32* __restrict__ rp, u32* __restrict__ bsum){
  __shared__ u32 sh[256];
  int t=threadIdx.x; int base=blockIdx.x*256;
  u32 v=cnt[base+t]; sh[t]=v;
  cnt[base+t]=0u;                       // re-zero cur for scatter
  __syncthreads();
  for(int off=1;off<256;off<<=1){
    u32 tv=(t>=off)?sh[t-off]:0u; __syncthreads();
    sh[t]+=tv; __syncthreads();
  }
  rp[base+t]=sh[t]-v;
  if(t==255) bsum[blockIdx.x]=sh[255];
}

__global__ void scan2b(u32* __restrict__ bsum, u32* __restrict__ rp){
  __shared__ u32 sh[256];
  int t=threadIdx.x;
  u32 v0=bsum[t*4+0],v1=bsum[t*4+1],v2=bsum[t*4+2],v3=bsum[t*4+3];
  u32 s=v0+v1+v2+v3;
  sh[t]=s; __syncthreads();
  for(int off=1;off<256;off<<=1){
    u32 tv=(t>=off)?sh[t-off]:0u; __syncthreads();
    sh[t]+=tv; __syncthreads();
  }
  u32 ex=sh[t]-s;
  bsum[t*4+0]=ex; bsum[t*4+1]=ex+v0; bsum[t*4+2]=ex+v0+v1; bsum[t*4+3]=ex+v0+v1+v2;
  if(t==0) rp[NS]=NE;
  if(t==255) bsum[1024]=0u;
}

__global__ void scatter_edges2(const int* __restrict__ src, const int* __restrict__ dst,
                               const int* __restrict__ et, const u32* __restrict__ rp,
                               const u32* __restrict__ bsum,
                               u32* __restrict__ cur, u32* __restrict__ adj){
  int e=blockIdx.x*256+threadIdx.x;
  int t=et[e];
  int d=dst[e];
  int key=(t>>1)*PASSB + d*2 + (t&1);
  u32 pos=atomicAdd(&cur[key],1u);
  u32 val=(u32)src[e] | (((u32)(((t&1)<<5)|(d&31)))<<15);   // src | localrow<<15
  adj[rp[key]+bsum[key>>8]+pos]=val;
}

// ---------------- fused_layer: R5 structure at 8 waves (2x gather TLP) ----------------
// 32-dst blocks, 512 thr (8 waves), 4 blocks/CU (32 KB LDS) -> 32 waves/CU.
// Per pass p: wave owns 4 dsts x 2 rels (8 contiguous keys); branchy register gather
// (R5 body verbatim, hi-only reads); FLUSH2 trunc-split into As hi/lo; GEMM rl 0..1
// with 2x4 wave tiling accumulating accR. Then self-GEMM (full hi/lo) + epilogue.
#define FLUSH2(rw) do{ \
  u32 u0=__float_as_uint(v0), u1=__float_as_uint(v1); \
  u32 t0=u0&0xffff0000u, t1=u1&0xffff0000u; \
  u32 hp=t1|(u0>>16); \
  float l0f=v0-__uint_as_float(t0), l1f=v1-__uint_as_float(t1); \
  u32 w0b=__float_as_uint(l0f), w1b=__float_as_uint(l1f); \
  u32 lp=(w1b&0xffff0000u)|(w0b>>16); \
  int fw=(rw)*64 + (((lane>>2)^((rw)&15))<<2) + (lane&3); \
  ((u32*)As[0])[fw]=hp; \
  ((u32*)As[1])[fw]=lp; \
}while(0)

__global__ __launch_bounds__(512,4) void fused_layer(
    const u16* __restrict__ xh, const u16* __restrict__ xl,
    const u16* __restrict__ Bp,
    const u32* __restrict__ rp, const u32* __restrict__ bsum,
    const u32* __restrict__ adj,
    const float* __restrict__ sb, const int* __restrict__ mask,
    u16* __restrict__ oh, u16* __restrict__ ol, float* __restrict__ outf, int last)
{
  __shared__ u16 As[2][64*128];     // 32 KB: [0]=hi [1]=lo; XOR-16 swizzled rows
  __shared__ float sdeg[32];
  const int tid=threadIdx.x;
  const int wave=tid>>6, lane=tid&63;
  const int wm=wave>>2, wn=wave&3;
  const int q=lane>>4;
  const int d0=blockIdx.x*32;
  const u32* xh32=(const u32*)xh;

  f32x4 accR[2];
  accR[0]=(f32x4){0.f,0.f,0.f,0.f};
  accR[1]=(f32x4){0.f,0.f,0.f,0.f};

  for(int p=0;p<4;p++){
    // zero owned rows: wave owns dsts [wave*4,wave*4+4), rl 0..1, both planes
    { uint4 zz={0u,0u,0u,0u};
#pragma unroll
      for(int rl=0;rl<2;rl++){
        int row=rl*32+wave*4+(lane>>4);
        int col16=lane&15;
        *(uint4*)&As[0][row*128+col16*8]=zz;
        *(uint4*)&As[1][row*128+col16*8]=zz;
      }
    }
    // gather: wave's 8-key contiguous range (4 dsts x 2 rels), scalar edge decode
    { u32 k0=(u32)(p*PASSB + (d0+wave*4)*2);
      u32 begW=rp[k0]+bsum[k0>>8];
      u32 k1=k0+8;
      u32 endW=rp[k1]+bsum[k1>>8];
      int currow=-1; float v0=0.f,v1=0.f;
      for(u32 base=begW; base<endW; base+=64){
        int nk=(int)(endW-base); if(nk>64) nk=64;
        u32 adjv=(lane<nk)?adj[base+lane]:0u;
        int i=0;
        for(; i+8<=nk; i+=8){
          u32 ww[8]; u32 hv[8];
#pragma unroll
          for(int j=0;j<8;j++){
            ww[j]=(u32)__builtin_amdgcn_readlane((int)adjv,i+j);
            hv[j]=xh32[(size_t)(ww[j]&0x7fffu)*64+lane];
          }
#pragma unroll
          for(int j=0;j<8;j++){
            int r=(int)(ww[j]>>15);
            if(r!=currow){ if(currow>=0) FLUSH2(currow); currow=r; v0=0.f; v1=0.f; }
            v0+=__uint_as_float(hv[j]<<16);
            v1+=__uint_as_float(hv[j]&0xffff0000u);
          }
        }
        for(; i<nk; i++){
          u32 w=(u32)__builtin_amdgcn_readlane((int)adjv,i);
          u32 h=xh32[(size_t)(w&0x7fffu)*64+lane];
          int r=(int)(w>>15);
          if(r!=currow){ if(currow>=0) FLUSH2(currow); currow=r; v0=0.f; v1=0.f; }
          v0+=__uint_as_float(h<<16);
          v1+=__uint_as_float(h&0xffff0000u);
        }
      }
      if(currow>=0) FLUSH2(currow);
    }
    __syncthreads();
    // GEMM relations 2p, 2p+1 — 2x4 wave tiling, accumulate over rl and passes
#pragma unroll
    for(int rl=0;rl<2;rl++){
      const u16* Bt=Bp+(size_t)(p*2+rl)*32768;
#pragma unroll
      for(int ks=0;ks<4;ks++){
        int ar=rl*32+wm*16+(lane&15);
        int off=ar*128+((((ks<<2)+q)^(ar&15))<<3);
        bf16x8 ah=*(const bf16x8*)&As[0][off];
        bf16x8 al=*(const bf16x8*)&As[1][off];
#pragma unroll
        for(int tn=0;tn<2;tn++){
          int n=wn*32+tn*16+(lane&15);
          size_t boff=((size_t)(ks*128+n))*32+q*8;
          bf16x8 bh=*(const bf16x8*)&Bt[boff];
          bf16x8 bl=*(const bf16x8*)&Bt[boff+16384];
          accR[tn]=__builtin_amdgcn_mfma_f32_16x16x32_bf16(ah,bh,accR[tn],0,0,0);
          accR[tn]=__builtin_amdgcn_mfma_f32_16x16x32_bf16(al,bh,accR[tn],0,0,0);
          accR[tn]=__builtin_amdgcn_mfma_f32_16x16x32_bf16(ah,bl,accR[tn],0,0,0);
        }
      }
    }
    __syncthreads();
  }

  // ---- self: waves 0-3 stage x-hi rows 0..31 -> As[0]; waves 4-7 x-lo -> As[1] ----
#pragma unroll
  for(int i=0;i<2;i++){
    int rbase=(wave&3)*8+i*4;
    int r=rbase+(lane>>4);
    int g=(lane&15)^(r&15);
    if(wave<4) gl_lds16(xh+(size_t)(d0+r)*HD+g*8, &As[0][rbase*128]);
    else       gl_lds16(xl+(size_t)(d0+r)*HD+g*8, &As[1][rbase*128]);
  }
  if(tid<32){
    int g=d0+tid; u32 dg=0;
#pragma unroll
    for(int ph=0;ph<4;ph++){
      u32 k=(u32)(ph*PASSB+g*2);
      dg+=(rp[k+2]+bsum[(k+2)>>8])-(rp[k]+bsum[k>>8]);
    }
    sdeg[tid]=1.f/fmaxf((float)dg,1.f);
  }
  __syncthreads();

  // ---- self-GEMM: full hi/lo A x hi/lo B ----
  f32x4 accS[2];
  accS[0]=(f32x4){0.f,0.f,0.f,0.f};
  accS[1]=(f32x4){0.f,0.f,0.f,0.f};
  { const u16* Bt=Bp+(size_t)8*32768;
#pragma unroll
    for(int ks=0;ks<4;ks++){
      int ar=wm*16+(lane&15);
      int off=ar*128+((((ks<<2)+q)^(ar&15))<<3);
      bf16x8 ah=*(const bf16x8*)&As[0][off];
      bf16x8 al=*(const bf16x8*)&As[1][off];
#pragma unroll
      for(int tn=0;tn<2;tn++){
        int n=wn*32+tn*16+(lane&15);
        size_t boff=((size_t)(ks*128+n))*32+q*8;
        bf16x8 bh=*(const bf16x8*)&Bt[boff];
        bf16x8 bl=*(const bf16x8*)&Bt[boff+16384];
        accS[tn]=__builtin_amdgcn_mfma_f32_16x16x32_bf16(ah,bh,accS[tn],0,0,0);
        accS[tn]=__builtin_amdgcn_mfma_f32_16x16x32_bf16(al,bh,accS[tn],0,0,0);
        accS[tn]=__builtin_amdgcn_mfma_f32_16x16x32_bf16(ah,bl,accS[tn],0,0,0);
      }
    }
  }

  // ---- epilogue: out = relu(accS + sb + accR/deg); rows wm*16+q*4+rr ----
#pragma unroll
  for(int tn=0;tn<2;tn++){
    int n=wn*32+tn*16+(lane&15);
    float bb=sb[n];
    if(last){
#pragma unroll
      for(int rr=0;rr<4;rr++){
        int row=wm*16+q*4+rr;
        float v=fmaxf(accS[tn][rr]+bb+accR[tn][rr]*sdeg[row],0.f);
        v*=(float)mask[d0+row];
        outf[(size_t)(d0+row)*HD+n]=v;
      }
    } else {
#pragma unroll
      for(int rr=0;rr<4;rr++){
        int row=wm*16+q*4+rr;
        float v=fmaxf(accS[tn][rr]+bb+accR[tn][rr]*sdeg[row],0.f);
        u16 hb=f2bf(v);
        u16 lb=f2bf(v-bf2f(hb));
        oh[(size_t)(d0+row)*HD+n]=hb;
        ol[(size_t)(d0+row)*HD+n]=lb;
      }
    }
  }
}

extern "C" void kernel_launch(void* const* d_in, const int* in_sizes, int n_in,
                              void* d_out, int out_size, void* d_ws, size_t ws_size,
                              hipStream_t stream)
{
  (void)in_sizes; (void)n_in; (void)out_size; (void)ws_size;
  const int*   cid =(const int*)  d_in[0];
  const int*   kid =(const int*)  d_in[1];
  const int*   mask=(const int*)  d_in[2];
  const int*   ei  =(const int*)  d_in[3];
  const int*   et  =(const int*)  d_in[4];
  const float* cemb=(const float*)d_in[5];
  const float* kemb=(const float*)d_in[6];
  const float* pW  =(const float*)d_in[7];
  const float* pb  =(const float*)d_in[8];
  const float* sW  =(const float*)d_in[9];
  const float* sb  =(const float*)d_in[10];
  const float* rW  =(const float*)d_in[11];
  float* out=(float*)d_out;
  char*  ws =(char*)d_ws;

  u16* xh =(u16*)(ws+XH_OFF);
  u16* xl =(u16*)(ws+XL_OFF);
  u16* xh2=(u16*)(ws+XH2_OFF);
  u16* xl2=(u16*)(ws+XL2_OFF);
  u32* adj =(u32*)(ws+ADJ_OFF);
  u32* rp  =(u32*)(ws+RP_OFF);
  u32* cur =(u32*)(ws+CUR_OFF);
  u32* bsum=(u32*)(ws+BSUM_OFF);
  u16* Bp  =(u16*)(ws+BP_OFF);
  const int* srcA=ei;
  const int* dstA=ei+NE;

  hipMemsetAsync(cur,0,NS*sizeof(u32),stream);
  prep_w<<<1216,256,0,stream>>>(rW,sW,pW,Bp);
  embed_mfma<<<NODES/64,256,0,stream>>>(cid,kid,cemb,kemb,Bp+PP_ELEM,pb,xh,xl);
  count_deg2<<<NE/256,256,0,stream>>>(dstA,et,cur);
  scan1<<<NS/256,256,0,stream>>>(cur,rp,bsum);
  scan2b<<<1,256,0,stream>>>(bsum,rp);
  scatter_edges2<<<NE/256,256,0,stream>>>(srcA,dstA,et,rp,bsum,cur,adj);

  fused_layer<<<NODES/32,512,0,stream>>>(xh,xl,Bp,rp,bsum,adj,sb,mask,(u16*)xh2,(u16*)xl2,out,0);
  fused_layer<<<NODES/32,512,0,stream>>>(xh2,xl2,Bp+BP_LAYER,rp,bsum,adj,sb+HD,mask,(u16*)xh,(u16*)xl,out,1);
}